// Round 7
// baseline (3759.883 us; speedup 1.0000x reference)
//
#include <hip/hip_runtime.h>
#include <hip/hip_bf16.h>
#include <cstdint>

// Problem constants
#define T_SEQ  4096
#define DMODEL 512
#define DINNER 1024
#define MTOT   32768            // B*T = 8*4096 rows

typedef __bf16 bf16_t;
typedef float f32x4 __attribute__((ext_vector_type(4)));

__device__ __forceinline__ float silu_f(float v) {
  return v / (1.f + __expf(-v));
}

__device__ __forceinline__ float ldf(const float* p)  { return *p; }
__device__ __forceinline__ float ldf(const bf16_t* p) { return (float)*p; }

// Textbook LDS-tiled GEMM, correctness-first (no MFMA, no global_load_lds).
// C[m,n] = sum_k A[m,k] * B[n,k]    (A: MxK row-major, B: NxK row-major)
// EPI 0: plain bf16 store
// EPI 1: +bias(f32), silu, bf16 store
// EPI 2: +resid(f32), f32 store
template <int EPI, typename TA, typename TB>
__global__ __launch_bounds__(256) void gemm_bt(
    const TA* __restrict__ A, const TB* __restrict__ B,
    bf16_t* __restrict__ Cb, float* __restrict__ Cf,
    const float* __restrict__ bias, const float* __restrict__ resid,
    int N, int K)
{
  constexpr int BM = 64, BN = 64, BK = 32, LDP = 68;
  __shared__ float sAT[BK * LDP];   // sAT[k][m]
  __shared__ float sBT[BK * LDP];   // sBT[k][n]

  const int tid = threadIdx.x;
  const int m0  = blockIdx.y * BM;
  const int n0  = blockIdx.x * BN;
  const int tm  = tid >> 4;         // 0..15 -> 4 rows each
  const int tn  = tid & 15;         // 0..15 -> 4 cols each

  float acc[4][4] = {};

  for (int kt = 0; kt < K; kt += BK) {
    __syncthreads();
    // stage 64x32 A-tile and B-tile, transposed into LDS
#pragma unroll
    for (int i = 0; i < 8; ++i) {
      const int e = i * 256 + tid;          // 0..2047
      const int r = e >> 5, c = e & 31;     // r: tile row, c: k within tile
      sAT[c * LDP + r] = ldf(&A[(size_t)(m0 + r) * K + kt + c]);
      sBT[c * LDP + r] = ldf(&B[(size_t)(n0 + r) * K + kt + c]);
    }
    __syncthreads();
#pragma unroll 8
    for (int k = 0; k < BK; ++k) {
      const f32x4 a = *(const f32x4*)&sAT[k * LDP + (tm << 2)];
      const f32x4 b = *(const f32x4*)&sBT[k * LDP + (tn << 2)];
#pragma unroll
      for (int i = 0; i < 4; ++i)
#pragma unroll
        for (int j = 0; j < 4; ++j)
          acc[i][j] += a[i] * b[j];
    }
  }

#pragma unroll
  for (int i = 0; i < 4; ++i)
#pragma unroll
    for (int j = 0; j < 4; ++j) {
      const int row = m0 + (tm << 2) + i;
      const int col = n0 + (tn << 2) + j;
      float v = acc[i][j];
      if constexpr (EPI == 0) {
        Cb[(size_t)row * N + col] = (bf16_t)v;
      } else if constexpr (EPI == 1) {
        v += bias[col];
        Cb[(size_t)row * N + col] = (bf16_t)silu_f(v);
      } else {
        v += resid[(size_t)row * N + col];
        Cf[(size_t)row * N + col] = v;
      }
    }
}

// Depthwise causal conv, one direction, shift_right folded in. Chunk-local.
// DIR=0: v[bt,c] = b[c] + sum_j w[c,6-j]*x_proj[bt-1-j,c]   (t-1-j >= 0)
// DIR=1: v[bt,c] = b[c] + sum_j w[c,6-j]*x_proj[bt+1+j,c]   (t+1+j <= T-1)
template <int DIR>
__global__ __launch_bounds__(256) void conv_kernel(
    const bf16_t* __restrict__ xzc,
    const float* __restrict__ wc, const float* __restrict__ bc,
    bf16_t* __restrict__ vout, int r0, int loc0)
{
  const int idx = blockIdx.x * 256 + threadIdx.x;   // over CH*DINNER
  const int c   = idx & (DINNER - 1);
  const int btl = idx >> 10;
  const int t   = (btl + r0) & (T_SEQ - 1);
  const int lt  = btl + loc0;                        // local row in xzc

  float wv[7];
#pragma unroll
  for (int k = 0; k < 7; ++k) wv[k] = wc[c * 7 + k];
  float a = bc[c];
#pragma unroll
  for (int j = 0; j < 7; ++j) {
    if constexpr (DIR == 0) {
      if (t - 1 - j >= 0)
        a += wv[6 - j] * (float)xzc[(size_t)(lt - 1 - j) * 2048 + c];
    } else {
      if (t + 1 + j < T_SEQ)
        a += wv[6 - j] * (float)xzc[(size_t)(lt + 1 + j) * 2048 + c];
    }
  }
  vout[idx] = (bf16_t)a;
}

// g = (sf*[t>0] + sb*[t<T-1] + xp*diag) * silu(z) * gs  -> in-place over sb
__global__ __launch_bounds__(256) void gate_kernel(
    const bf16_t* __restrict__ xzc,
    const bf16_t* __restrict__ sf, bf16_t* __restrict__ sb_g,
    const float* __restrict__ diag, const float* __restrict__ gs,
    int r0, int loc0)
{
  const int idx = blockIdx.x * 256 + threadIdx.x;   // over CH*DINNER
  const int e   = idx & (DINNER - 1);
  const int btl = idx >> 10;
  const int t   = (btl + r0) & (T_SEQ - 1);
  const int lt  = btl + loc0;

  const float xp = (float)xzc[(size_t)lt * 2048 + e];
  const float z  = (float)xzc[(size_t)lt * 2048 + DINNER + e];
  float y = xp * diag[e];
  if (t > 0)         y += (float)sf[idx];
  if (t < T_SEQ - 1) y += (float)sb_g[idx];
  sb_g[idx] = (bf16_t)(y * silu_f(z) * gs[0]);
}

// LayerNorm over D=512, one block (256 threads) per chunk-local row.
// h fp32 in, OUTPUT IS FP32 (reference output dtype is float32).
__global__ __launch_bounds__(256) void ln_kernel(
    const float* __restrict__ h,
    const float* __restrict__ lng, const float* __restrict__ lnb,
    float* __restrict__ out, int r0)
{
  const int row = blockIdx.x;                        // local row
  const int tid = threadIdx.x;
  const float* hr = h + (size_t)row * DMODEL;
  const float v0 = hr[tid], v1 = hr[tid + 256];
  float s  = v0 + v1;
  float ss = v0 * v0 + v1 * v1;
#pragma unroll
  for (int off = 1; off < 64; off <<= 1) {
    s  += __shfl_xor(s, off);
    ss += __shfl_xor(ss, off);
  }
  __shared__ float ps[8];
  const int w = tid >> 6;
  if ((tid & 63) == 0) { ps[w] = s; ps[w + 4] = ss; }
  __syncthreads();
  s  = ps[0] + ps[1] + ps[2] + ps[3];
  ss = ps[4] + ps[5] + ps[6] + ps[7];
  const float mu  = s * (1.f / DMODEL);
  const float inv = rsqrtf(ss * (1.f / DMODEL) - mu * mu + 1e-5f);
  float* o = out + (size_t)(r0 + row) * DMODEL;
  o[tid]       = (v0 - mu) * inv * lng[tid]       + lnb[tid];
  o[tid + 256] = (v1 - mu) * inv * lng[tid + 256] + lnb[tid + 256];
}

extern "C" void kernel_launch(void* const* d_in, const int* in_sizes, int n_in,
                              void* d_out, int out_size, void* d_ws, size_t ws_size,
                              hipStream_t stream) {
  // Inputs fp32 (reference setup_inputs dtypes); OUTPUT fp32 (reference
  // return dtype). The "(bf16)" in the harness label is comparison mode,
  // not storage: writing bf16 into the fp32 out buffer gave the exact
  // decorrelated-garbage signature (absmax 7.69 = sqrt2*5.4sigma) in R5/R6.
  const float* x    = (const float*)d_in[0];
  const float* in_w = (const float*)d_in[1];
  const float* cfw  = (const float*)d_in[2];
  const float* cfb  = (const float*)d_in[3];
  const float* pfw  = (const float*)d_in[4];
  const float* pfb  = (const float*)d_in[5];
  const float* cbw  = (const float*)d_in[6];
  const float* cbb  = (const float*)d_in[7];
  const float* pbw  = (const float*)d_in[8];
  const float* pbb  = (const float*)d_in[9];
  const float* diag = (const float*)d_in[10];
  const float* gs   = (const float*)d_in[11];
  const float* ow   = (const float*)d_in[12];
  const float* lng  = (const float*)d_in[13];
  const float* lnb  = (const float*)d_in[14];
  float* out = (float*)d_out;

  // Workspace-adaptive chunking over M. Conv needs +-7 row halo -> recompute
  // one extra 128-row GEMM1 slab per side.
  // req(CH) = (CH+256)*4096 + 3*CH*2048 bytes.
  int CH = 128;
  {
    const int cands[8] = {16384, 8192, 4096, 2048, 1024, 512, 256, 128};
    for (int i = 0; i < 8; ++i) {
      const size_t req = (size_t)(cands[i] + 256) * 4096 +
                         (size_t)3 * cands[i] * 2048;
      if (ws_size >= req) { CH = cands[i]; break; }
    }
  }

  char* cb = (char*)d_ws;
  const size_t xz_cap = (size_t)(CH + 256) * 4096;      // bytes
  bf16_t* xzc  = (bf16_t*)cb;
  bf16_t* bufA = (bf16_t*)(cb + xz_cap);
  bf16_t* bufB = (bf16_t*)(cb + xz_cap + (size_t)CH * 2048);
  bf16_t* bufC = (bf16_t*)(cb + xz_cap + (size_t)CH * 4096);
  float*  hbuf = (float*)cb;                             // aliases xzc (dead by then)

  dim3 blk(256);

  for (int r0 = 0; r0 < MTOT; r0 += CH) {
    const int g0 = (r0 >= 128) ? (r0 - 128) : 0;
    int g1 = r0 + CH + 128; if (g1 > MTOT) g1 = MTOT;
    const int Mc   = g1 - g0;        // multiple of 128
    const int loc0 = r0 - g0;        // chunk start's local row in xzc

    // 1) xzc = x[g0:g1] @ in_proj_w^T        (Mc x 2048, K=512)
    gemm_bt<0, float, float><<<dim3(2048 / 64, Mc / 64), blk, 0, stream>>>(
        x + (size_t)g0 * 512, in_w, xzc, nullptr, nullptr, nullptr, 2048, 512);

    // 2) forward shifted causal conv -> v_fwd (bufA)
    conv_kernel<0><<<dim3((CH * DINNER) / 256), blk, 0, stream>>>(
        xzc, cfw, cfb, bufA, r0, loc0);

    // 3) s_fwd = silu(v_fwd @ Pf^T + bf) -> bufB   (N=1024, K=1024)
    gemm_bt<1, bf16_t, float><<<dim3(1024 / 64, CH / 64), blk, 0, stream>>>(
        bufA, pfw, bufB, nullptr, pfb, nullptr, 1024, 1024);

    // 4) backward shifted causal conv -> v_bwd (bufA, v_fwd dead)
    conv_kernel<1><<<dim3((CH * DINNER) / 256), blk, 0, stream>>>(
        xzc, cbw, cbb, bufA, r0, loc0);

    // 5) s_bwd = silu(v_bwd @ Pb^T + bb) -> bufC
    gemm_bt<1, bf16_t, float><<<dim3(1024 / 64, CH / 64), blk, 0, stream>>>(
        bufA, pbw, bufC, nullptr, pbb, nullptr, 1024, 1024);

    // 6) gate: g = (sf*[t>0]+sb*[t<T-1]+xp*diag)*silu(z)*gs -> bufC in-place
    gate_kernel<<<dim3((CH * DINNER) / 256), blk, 0, stream>>>(
        xzc, bufB, bufC, diag, gs, r0, loc0);

    // 7) h = x + g @ out_proj^T (fp32) -> hbuf (aliases xzc; xz dead now)
    gemm_bt<2, bf16_t, float><<<dim3(512 / 64, CH / 64), blk, 0, stream>>>(
        bufC, ow, nullptr, hbuf, nullptr, x + (size_t)r0 * 512, 512, 1024);

    // 8) LayerNorm -> out rows [r0, r0+CH)   (fp32 store)
    ln_kernel<<<dim3(CH), blk, 0, stream>>>(hbuf, lng, lnb, out, r0);
  }
}

// Round 8
// 970.750 us; speedup vs baseline: 3.8732x; 3.8732x over previous
//
#include <hip/hip_runtime.h>
#include <hip/hip_bf16.h>
#include <cstdint>

// Problem constants
#define T_SEQ  4096
#define DMODEL 512
#define DINNER 1024
#define MTOT   32768            // B*T = 8*4096 rows

typedef __bf16 bf16_t;
typedef bf16_t bf16x8 __attribute__((ext_vector_type(8)));
typedef bf16_t bf16x4v __attribute__((ext_vector_type(4)));
typedef float  f32x4  __attribute__((ext_vector_type(4)));

__device__ __forceinline__ void async_copy16(const bf16_t* g, bf16_t* l) {
  __builtin_amdgcn_global_load_lds(
      (const __attribute__((address_space(1))) void*)g,
      (__attribute__((address_space(3))) void*)l,
      16, 0, 0);
}

__device__ __forceinline__ float silu_f(float v) {
  return v / (1.f + __expf(-v));
}

// fp32 -> bf16 cast, 4 elements/thread
__global__ __launch_bounds__(256) void cast_kernel(
    const float* __restrict__ s, bf16_t* __restrict__ d, int n4)
{
  const int i = blockIdx.x * 256 + threadIdx.x;
  if (i < n4) {
    const f32x4 v = ((const f32x4*)s)[i];
    bf16x4v o;
    o[0] = (bf16_t)v[0]; o[1] = (bf16_t)v[1];
    o[2] = (bf16_t)v[2]; o[3] = (bf16_t)v[3];
    ((bf16x4v*)d)[i] = o;
  }
}

// MFMA GEMM (m97 structure): C[m,n] = sum_k A[m,k]*B[n,k]
// A: MxK row-major bf16, B: NxK row-major bf16.
// EPI 0: plain bf16 store
// EPI 1: +bias(f32), silu, bf16 store
// EPI 2: +resid(f32), f32 store
template <int EPI>
__global__ __launch_bounds__(256, 2) void gemm_bt(
    const bf16_t* __restrict__ A, const bf16_t* __restrict__ B,
    bf16_t* __restrict__ Cb, float* __restrict__ Cf,
    const float* __restrict__ bias, const float* __restrict__ resid,
    int N, int K)
{
  constexpr int BM = 128, BN = 128, BK = 64;
  __shared__ __attribute__((aligned(16))) bf16_t sA[BM * BK];
  __shared__ __attribute__((aligned(16))) bf16_t sB[BN * BK];

  const int tid  = threadIdx.x;
  const int m0   = blockIdx.y * BM;
  const int n0   = blockIdx.x * BN;
  const int w    = tid >> 6, lane = tid & 63;
  const int wm   = (w & 1) << 6, wn = (w >> 1) << 6;   // 2x2 waves -> 64x64 each
  const int quad = lane >> 4, lrow = lane & 15;

  f32x4 acc[4][4] = {};

  for (int kt = 0; kt < K; kt += BK) {
    __syncthreads();   // protect LDS while prior tile in use
#pragma unroll
    for (int i = 0; i < 4; ++i) {
      const int f = (i * 256 + tid) << 3;    // flat bf16 index in 128x64 tile
      const int r = f >> 6, c = f & 63;
      async_copy16(&A[(size_t)(m0 + r) * K + kt + c], &sA[f]);
      async_copy16(&B[(size_t)(n0 + r) * K + kt + c], &sB[f]);
    }
    __syncthreads();   // vmcnt(0) drain happens here
#pragma unroll
    for (int ks = 0; ks < 2; ++ks) {
      bf16x8 av[4], bv[4];
#pragma unroll
      for (int i = 0; i < 4; ++i) {
        av[i] = *(const bf16x8*)&sA[(wm + i * 16 + lrow) * BK + ks * 32 + (quad << 3)];
        bv[i] = *(const bf16x8*)&sB[(wn + i * 16 + lrow) * BK + ks * 32 + (quad << 3)];
      }
#pragma unroll
      for (int mi = 0; mi < 4; ++mi)
#pragma unroll
        for (int ni = 0; ni < 4; ++ni)
          acc[mi][ni] = __builtin_amdgcn_mfma_f32_16x16x32_bf16(
              av[mi], bv[ni], acc[mi][ni], 0, 0, 0);
    }
  }

  // C/D layout: col = lane&15, row = quad*4 + reg   [m89/m91 verified]
#pragma unroll
  for (int mi = 0; mi < 4; ++mi)
#pragma unroll
    for (int ni = 0; ni < 4; ++ni)
#pragma unroll
      for (int r = 0; r < 4; ++r) {
        const int row = m0 + wm + mi * 16 + (quad << 2) + r;
        const int col = n0 + wn + ni * 16 + lrow;
        float v = acc[mi][ni][r];
        if constexpr (EPI == 0) {
          Cb[(size_t)row * N + col] = (bf16_t)v;
        } else if constexpr (EPI == 1) {
          v += bias[col];
          Cb[(size_t)row * N + col] = (bf16_t)silu_f(v);
        } else {
          v += resid[(size_t)row * N + col];
          Cf[(size_t)row * N + col] = v;
        }
      }
}

// Depthwise causal conv, one direction, shift_right folded in. Chunk-local.
// DIR=0: v[bt,c] = b[c] + sum_j w[c,6-j]*x_proj[bt-1-j,c]   (t-1-j >= 0)
// DIR=1: v[bt,c] = b[c] + sum_j w[c,6-j]*x_proj[bt+1+j,c]   (t+1+j <= T-1)
template <int DIR>
__global__ __launch_bounds__(256) void conv_kernel(
    const bf16_t* __restrict__ xzc,
    const float* __restrict__ wc, const float* __restrict__ bc,
    bf16_t* __restrict__ vout, int r0, int loc0)
{
  const int idx = blockIdx.x * 256 + threadIdx.x;   // over CH*DINNER
  const int c   = idx & (DINNER - 1);
  const int btl = idx >> 10;
  const int t   = (btl + r0) & (T_SEQ - 1);
  const int lt  = btl + loc0;                        // local row in xzc

  float wv[7];
#pragma unroll
  for (int k = 0; k < 7; ++k) wv[k] = wc[c * 7 + k];
  float a = bc[c];
#pragma unroll
  for (int j = 0; j < 7; ++j) {
    if constexpr (DIR == 0) {
      if (t - 1 - j >= 0)
        a += wv[6 - j] * (float)xzc[(size_t)(lt - 1 - j) * 2048 + c];
    } else {
      if (t + 1 + j < T_SEQ)
        a += wv[6 - j] * (float)xzc[(size_t)(lt + 1 + j) * 2048 + c];
    }
  }
  vout[idx] = (bf16_t)a;
}

// g = (sf*[t>0] + sb*[t<T-1] + xp*diag) * silu(z) * gs  -> in-place over sb
__global__ __launch_bounds__(256) void gate_kernel(
    const bf16_t* __restrict__ xzc,
    const bf16_t* __restrict__ sf, bf16_t* __restrict__ sb_g,
    const float* __restrict__ diag, const float* __restrict__ gs,
    int r0, int loc0)
{
  const int idx = blockIdx.x * 256 + threadIdx.x;   // over CH*DINNER
  const int e   = idx & (DINNER - 1);
  const int btl = idx >> 10;
  const int t   = (btl + r0) & (T_SEQ - 1);
  const int lt  = btl + loc0;

  const float xp = (float)xzc[(size_t)lt * 2048 + e];
  const float z  = (float)xzc[(size_t)lt * 2048 + DINNER + e];
  float y = xp * diag[e];
  if (t > 0)         y += (float)sf[idx];
  if (t < T_SEQ - 1) y += (float)sb_g[idx];
  sb_g[idx] = (bf16_t)(y * silu_f(z) * gs[0]);
}

// LayerNorm over D=512, one block (256 threads) per chunk-local row.
// h fp32 in, fp32 out.
__global__ __launch_bounds__(256) void ln_kernel(
    const float* __restrict__ h,
    const float* __restrict__ lng, const float* __restrict__ lnb,
    float* __restrict__ out, int r0)
{
  const int row = blockIdx.x;                        // local row
  const int tid = threadIdx.x;
  const float* hr = h + (size_t)row * DMODEL;
  const float v0 = hr[tid], v1 = hr[tid + 256];
  float s  = v0 + v1;
  float ss = v0 * v0 + v1 * v1;
#pragma unroll
  for (int off = 1; off < 64; off <<= 1) {
    s  += __shfl_xor(s, off);
    ss += __shfl_xor(ss, off);
  }
  __shared__ float ps[8];
  const int w = tid >> 6;
  if ((tid & 63) == 0) { ps[w] = s; ps[w + 4] = ss; }
  __syncthreads();
  s  = ps[0] + ps[1] + ps[2] + ps[3];
  ss = ps[4] + ps[5] + ps[6] + ps[7];
  const float mu  = s * (1.f / DMODEL);
  const float inv = rsqrtf(ss * (1.f / DMODEL) - mu * mu + 1e-5f);
  float* o = out + (size_t)(r0 + row) * DMODEL;
  o[tid]       = (v0 - mu) * inv * lng[tid]       + lnb[tid];
  o[tid + 256] = (v1 - mu) * inv * lng[tid + 256] + lnb[tid + 256];
}

extern "C" void kernel_launch(void* const* d_in, const int* in_sizes, int n_in,
                              void* d_out, int out_size, void* d_ws, size_t ws_size,
                              hipStream_t stream) {
  // Inputs fp32; OUTPUT fp32 (verified passing in R7).
  const float* x    = (const float*)d_in[0];
  const float* in_w = (const float*)d_in[1];
  const float* cfw  = (const float*)d_in[2];
  const float* cfb  = (const float*)d_in[3];
  const float* pfw  = (const float*)d_in[4];
  const float* pfb  = (const float*)d_in[5];
  const float* cbw  = (const float*)d_in[6];
  const float* cbb  = (const float*)d_in[7];
  const float* pbw  = (const float*)d_in[8];
  const float* pbb  = (const float*)d_in[9];
  const float* diag = (const float*)d_in[10];
  const float* gs   = (const float*)d_in[11];
  const float* ow   = (const float*)d_in[12];
  const float* lng  = (const float*)d_in[13];
  const float* lnb  = (const float*)d_in[14];
  float* out = (float*)d_out;

  char* ws = (char*)d_ws;

  // Persistent bf16 copies of GEMM operand tensors (39 MiB):
  bf16_t* xw   = (bf16_t*)(ws);                         // 32768x512   (32 MiB)
  bf16_t* inwb = (bf16_t*)(ws + (size_t)33554432);      // 2048x512    (2 MiB)
  bf16_t* pfwb = (bf16_t*)(ws + (size_t)35651584);      // 1024x1024   (2 MiB)
  bf16_t* pbwb = (bf16_t*)(ws + (size_t)37748736);      // 1024x1024   (2 MiB)
  bf16_t* owb  = (bf16_t*)(ws + (size_t)39845888);      // 512x1024    (1 MiB)
  const size_t persist = 40894464;                      // 39 MiB

  // Workspace-adaptive chunking (R7 proved ws >= 169 MB -> CH >= 8192 here).
  // req(CH) = persist + (CH+256)*4096 + 3*CH*2048 bytes
  int CH = 128;
  {
    const int cands[8] = {16384, 8192, 4096, 2048, 1024, 512, 256, 128};
    for (int i = 0; i < 8; ++i) {
      const size_t req = persist + (size_t)(cands[i] + 256) * 4096 +
                         (size_t)3 * cands[i] * 2048;
      if (ws_size >= req) { CH = cands[i]; break; }
    }
  }

  char* cb = ws + persist;
  const size_t xz_cap = (size_t)(CH + 256) * 4096;      // bytes
  bf16_t* xzc  = (bf16_t*)cb;
  bf16_t* bufA = (bf16_t*)(cb + xz_cap);
  bf16_t* bufB = (bf16_t*)(cb + xz_cap + (size_t)CH * 2048);
  bf16_t* bufC = (bf16_t*)(cb + xz_cap + (size_t)CH * 4096);
  float*  hbuf = (float*)cb;                             // aliases xzc (dead by then)

  dim3 blk(256);

  // 0) one-time fp32 -> bf16 casts of GEMM operands
  cast_kernel<<<dim3(16384), blk, 0, stream>>>(x,    xw,   4194304);
  cast_kernel<<<dim3(1024),  blk, 0, stream>>>(in_w, inwb, 262144);
  cast_kernel<<<dim3(1024),  blk, 0, stream>>>(pfw,  pfwb, 262144);
  cast_kernel<<<dim3(1024),  blk, 0, stream>>>(pbw,  pbwb, 262144);
  cast_kernel<<<dim3(512),   blk, 0, stream>>>(ow,   owb,  131072);

  for (int r0 = 0; r0 < MTOT; r0 += CH) {
    const int g0 = (r0 >= 128) ? (r0 - 128) : 0;
    int g1 = r0 + CH + 128; if (g1 > MTOT) g1 = MTOT;
    const int Mc   = g1 - g0;        // multiple of 128
    const int loc0 = r0 - g0;        // chunk start's local row in xzc

    // 1) xzc = x[g0:g1] @ in_proj_w^T        (Mc x 2048, K=512)
    gemm_bt<0><<<dim3(2048 / 128, Mc / 128), blk, 0, stream>>>(
        xw + (size_t)g0 * 512, inwb, xzc, nullptr, nullptr, nullptr, 2048, 512);

    // 2) forward shifted causal conv -> v_fwd (bufA)
    conv_kernel<0><<<dim3((CH * DINNER) / 256), blk, 0, stream>>>(
        xzc, cfw, cfb, bufA, r0, loc0);

    // 3) s_fwd = silu(v_fwd @ Pf^T + bf) -> bufB   (N=1024, K=1024)
    gemm_bt<1><<<dim3(1024 / 128, CH / 128), blk, 0, stream>>>(
        bufA, pfwb, bufB, nullptr, pfb, nullptr, 1024, 1024);

    // 4) backward shifted causal conv -> v_bwd (bufA, v_fwd dead)
    conv_kernel<1><<<dim3((CH * DINNER) / 256), blk, 0, stream>>>(
        xzc, cbw, cbb, bufA, r0, loc0);

    // 5) s_bwd = silu(v_bwd @ Pb^T + bb) -> bufC
    gemm_bt<1><<<dim3(1024 / 128, CH / 128), blk, 0, stream>>>(
        bufA, pbwb, bufC, nullptr, pbb, nullptr, 1024, 1024);

    // 6) gate: g = (sf*[t>0]+sb*[t<T-1]+xp*diag)*silu(z)*gs -> bufC in-place
    gate_kernel<<<dim3((CH * DINNER) / 256), blk, 0, stream>>>(
        xzc, bufB, bufC, diag, gs, r0, loc0);

    // 7) h = x + g @ out_proj^T (fp32) -> hbuf (aliases xzc; xz dead now)
    gemm_bt<2><<<dim3(512 / 128, CH / 128), blk, 0, stream>>>(
        bufC, owb, nullptr, hbuf, nullptr, x + (size_t)r0 * 512, 512, 1024);

    // 8) LayerNorm -> out rows [r0, r0+CH)   (fp32 store)
    ln_kernel<<<dim3(CH), blk, 0, stream>>>(hbuf, lng, lnb, out, r0);
  }
}